// Round 14
// baseline (94.753 us; speedup 1.0000x reference)
//
#include <hip/hip_runtime.h>
#include <hip/hip_bf16.h>
#include <stdint.h>

typedef __attribute__((ext_vector_type(8))) short short8;
typedef __attribute__((ext_vector_type(4))) float f32x4;

#define NB 128
#define NL 256
#define NROWS 32768        // B*L
#define IN_DIM 360
#define KP1 384            // padded K for layer-1 GEMM (permuted layout)
#define MEM 200
#define NP 256             // padded N
#define OUT_X (NROWS * MEM)
#define YTP 264            // Yt pitch in bf16 (528 B rows)
#define BUFSZ 16384        // one A staging buffer (256x32 bf16)
#define YTOFF 32768        // Yt offset in smem

// Permuted K layout for x/W0p (keeps every 8-col chunk single-table):
//   kp 0..299 emb | kp 304..333 pos | kp 336..365 ner | else zero
// Chunk id c = kp/8: 0..36 emb-full | 37 emb-tail | 38..41 pos | 42..45 ner | 46,47 zero

__device__ __forceinline__ unsigned short f2b(float f) {
    unsigned u = __builtin_bit_cast(unsigned, f);
    unsigned r = (u + 0x7FFFu + ((u >> 16) & 1u)) >> 16;
    return (unsigned short)r;
}

// gather one 8-col chunk of the (permuted) embedding row as bf16
__device__ __forceinline__ short8 gather_chunk(int chunk, const float* __restrict__ er,
                                               const float* __restrict__ pr,
                                               const float* __restrict__ nr) {
    float v[8];
    if (chunk < 37) {                                   // emb, 16B-aligned (stride 1200 B)
        const float* s = er + chunk * 8;
        float4 a = *(const float4*)s;
        float4 b = *(const float4*)(s + 4);
        v[0] = a.x; v[1] = a.y; v[2] = a.z; v[3] = a.w;
        v[4] = b.x; v[5] = b.y; v[6] = b.z; v[7] = b.w;
    } else if (chunk == 37) {                           // emb tail 296..299 + pad
        float4 a = *(const float4*)(er + 296);
        v[0] = a.x; v[1] = a.y; v[2] = a.z; v[3] = a.w;
        v[4] = 0.f; v[5] = 0.f; v[6] = 0.f; v[7] = 0.f;
    } else if (chunk <= 41) {                           // pos (stride 120 B: scalar, guarded)
        int k0 = chunk * 8 - 304;
        #pragma unroll
        for (int i = 0; i < 8; ++i) v[i] = (k0 + i < 30) ? pr[k0 + i] : 0.f;
    } else if (chunk <= 45) {                           // ner
        int k0 = chunk * 8 - 336;
        #pragma unroll
        for (int i = 0; i < 8; ++i) v[i] = (k0 + i < 30) ? nr[k0 + i] : 0.f;
    } else {
        #pragma unroll
        for (int i = 0; i < 8; ++i) v[i] = 0.f;
    }
    short8 r;
    #pragma unroll
    for (int i = 0; i < 8; ++i) r[i] = (short)f2b(v[i]);
    return r;
}

// ---------------- weight prep + colnz zero
__global__ void prep_weights(const float* __restrict__ W0, const float* __restrict__ W1,
                             short* __restrict__ W0p, short* __restrict__ W1p,
                             unsigned* __restrict__ colnz) {
    int idx = blockIdx.x * 256 + threadIdx.x;
    if (idx < NROWS) colnz[idx] = 0u;
    if (idx < NP * KP1) {
        int n = idx / KP1, kp = idx - n * KP1;
        float v = 0.f;
        if (n < MEM) {
            if (kp < 300)                   v = W0[n * IN_DIM + kp];
            else if (kp >= 304 && kp < 334) v = W0[n * IN_DIM + 300 + (kp - 304)];
            else if (kp >= 336 && kp < 366) v = W0[n * IN_DIM + 330 + (kp - 336)];
        }
        W0p[idx] = (short)f2b(v);
    } else {
        int i2 = idx - NP * KP1;
        if (i2 < NP * NP) {
            int n = i2 >> 8, k = i2 & 255;
            float v = (n < MEM && k < MEM) ? W1[n * MEM + k] : 0.f;
            W1p[i2] = (short)f2b(v);
        }
    }
}

// ---------------- adj row pass: rowsum/dinv, S = (A+I) bf16 [B][256][256], colnz flags
__global__ void adjrow_kernel(const float* __restrict__ adj, float* __restrict__ dinv,
                              float* __restrict__ rsum, unsigned short* __restrict__ Sbf,
                              unsigned* __restrict__ colnz) {
    int row = blockIdx.x * 4 + (threadIdx.x >> 6);
    int lane = threadIdx.x & 63;
    const float4* ar = (const float4*)(adj + (size_t)row * NL);
    float4 v = ar[lane];
    float s = v.x + v.y + v.z + v.w;
    #pragma unroll
    for (int off = 32; off >= 1; off >>= 1) s += __shfl_xor(s, off);
    int rloc = row & 255;
    float d0 = v.x + ((lane * 4 + 0) == rloc ? 1.f : 0.f);
    float d1 = v.y + ((lane * 4 + 1) == rloc ? 1.f : 0.f);
    float d2 = v.z + ((lane * 4 + 2) == rloc ? 1.f : 0.f);
    float d3 = v.w + ((lane * 4 + 3) == rloc ? 1.f : 0.f);
    ushort4 st; st.x = f2b(d0); st.y = f2b(d1); st.z = f2b(d2); st.w = f2b(d3);
    *(ushort4*)(Sbf + (size_t)row * NL + lane * 4) = st;
    if (lane == 0) { rsum[row] = s; dinv[row] = 1.0f / (s + 1.0f); }
    unsigned* cz = colnz + ((row >> 8) << 8);
    if (v.x != 0.f) atomicOr(&cz[lane * 4 + 0], 1u);
    if (v.y != 0.f) atomicOr(&cz[lane * 4 + 1], 1u);
    if (v.z != 0.f) atomicOr(&cz[lane * 4 + 2], 1u);
    if (v.w != 0.f) atomicOr(&cz[lane * 4 + 3], 1u);
}

// ---------------- FUSED per-layer, all-MFMA. A through LDS (dbuf); B and S operands
// DIRECT FROM GLOBAL (L2-resident, 1-deep register prefetch) — identical fragments to the
// old swizzled-LDS path (row-major k-contiguous short8), half the LDS traffic, and
// phase 2b needs no staging -> no barriers at all.
// FINAL=0: A staging IS the embedding gather; also writes the mask (folded mask_kernel).
// N-slice 64 (grid 512 = 2 blocks/CU); 8 waves 4x2, wave tile 64x32, acc[4][2].
template <int FINAL>
__global__ __launch_bounds__(512, 4) void fused_kernel(
    const short* __restrict__ A, int lda, int nkt,
    const short* __restrict__ Bp, int ldb,
    const unsigned short* __restrict__ Sbf,
    const float* __restrict__ dinv, const float* __restrict__ bias,
    const int* __restrict__ words, const int* __restrict__ pos, const int* __restrict__ ner,
    const float* __restrict__ embW, const float* __restrict__ posW,
    const float* __restrict__ nerW,
    const float* __restrict__ rsum, const unsigned* __restrict__ colnz,
    float* __restrict__ maskout,
    short* __restrict__ x1b, float* __restrict__ outx) {
    extern __shared__ char smem[];
    unsigned short* Yt = (unsigned short*)(smem + YTOFF);   // [64][YTP] bf16

    int bi = blockIdx.x;
    int batch = bi & 127, sl = bi >> 7;                 // 4 slices of a batch -> same XCD

    int tid = threadIdx.x;
    int lane = tid & 63, wid = tid >> 6;
    int wr = wid >> 1, wc = wid & 1;                    // 4 x 2 wave grid
    int lr = lane & 15, lc = lane >> 4;

    // folded mask_kernel (FINAL=0, slice-0 blocks only; inputs ready at launch)
    if (FINAL == 0 && sl == 0 && tid < 256) {
        int r = batch * NL + tid;
        maskout[r] = (rsum[r] == 0.f && colnz[r] == 0u) ? 1.0f : 0.0f;
    }

    const short* Sb = (const short*)(Sbf + (size_t)batch * NL * NL);

    // A staging slots (byte offsets within a buffer)
    int r0s = tid >> 2, c0s = tid & 3;
    int r1s = r0s + 128;
    int offA0 = r0s * 64 + (c0s ^ ((r0s >> 1) & 3)) * 16;
    int offA1 = r1s * 64 + (c0s ^ ((r1s >> 1) & 3)) * 16;

    // B operand: direct global, per-wave row pointers (k-contiguous short8 = same fragment
    // the swizzled-LDS read produced)
    const short* Bf0 = Bp + (size_t)(sl * 64 + wc * 32 + lr) * ldb + lc * 8;
    const short* Bf1 = Bf0 + (size_t)16 * ldb;
    // S operand (phase 2b): rows = out-rows of this wave
    const short* Sw0 = Sb + (size_t)(wid * 32 + lr) * NL + lc * 8;
    const short* Sw1 = Sw0 + (size_t)16 * NL;

    // A source: FINAL=0 -> per-row table pointers; FINAL=1 -> X1b pointers
    const short* Ap0 = nullptr; const short* Ap1 = nullptr;
    const float *er0 = nullptr, *pr0 = nullptr, *nr0 = nullptr;
    const float *er1 = nullptr, *pr1 = nullptr, *nr1 = nullptr;
    if (FINAL == 0) {
        int g0 = batch * NL + r0s, g1 = g0 + 128;
        er0 = embW + (size_t)words[g0] * 300;
        pr0 = posW + (size_t)pos[g0] * 30;
        nr0 = nerW + (size_t)ner[g0] * 30;
        er1 = embW + (size_t)words[g1] * 300;
        pr1 = posW + (size_t)pos[g1] * 30;
        nr1 = nerW + (size_t)ner[g1] * 30;
    } else {
        const short* Ab = A + (size_t)batch * NL * lda;
        Ap0 = Ab + (size_t)r0s * lda + c0s * 8;
        Ap1 = Ab + (size_t)r1s * lda + c0s * 8;
    }
    #define LOADA(kt, o0, o1) do {                                  \
        if (FINAL == 0) {                                           \
            int ch_ = (kt) * 4 + c0s;                               \
            (o0) = gather_chunk(ch_, er0, pr0, nr0);                \
            (o1) = gather_chunk(ch_, er1, pr1, nr1);                \
        } else {                                                    \
            (o0) = *(const short8*)(Ap0 + (kt) * 32);               \
            (o1) = *(const short8*)(Ap1 + (kt) * 32);               \
        }                                                           \
    } while (0)

    f32x4 acc[4][2] = {};
    // prologue: A tile 0 -> buf0; load A tile 1; load B tile 0 frags
    short8 aR0, aR1;
    LOADA(0, aR0, aR1);
    *(short8*)(smem + offA0) = aR0;
    *(short8*)(smem + offA1) = aR1;
    LOADA(1, aR0, aR1);
    short8 bf0 = *(const short8*)Bf0;
    short8 bf1 = *(const short8*)Bf1;
    __syncthreads();

    for (int kt = 0; kt < nkt; ++kt) {
        char* base_ = smem + (kt & 1) * BUFSZ;
        short8 af[4];
        #pragma unroll
        for (int mi = 0; mi < 4; ++mi) {
            int row = wr * 64 + mi * 16 + lr;
            int cs = lc ^ ((row >> 1) & 3);
            af[mi] = *(const short8*)(base_ + row * 64 + cs * 16);
        }
        if (kt + 1 < nkt) {                             // write A tile kt+1 to other buffer
            char* nb_ = smem + ((kt + 1) & 1) * BUFSZ;
            *(short8*)(nb_ + offA0) = aR0;
            *(short8*)(nb_ + offA1) = aR1;
        }
        if (kt + 2 < nkt) LOADA(kt + 2, aR0, aR1);      // prefetch A tile kt+2
        short8 bf0n, bf1n;
        if (kt + 1 < nkt) {                             // prefetch B tile kt+1 (L2)
            bf0n = *(const short8*)(Bf0 + (kt + 1) * 32);
            bf1n = *(const short8*)(Bf1 + (kt + 1) * 32);
        }
        #pragma unroll
        for (int mi = 0; mi < 4; ++mi) {
            acc[mi][0] = __builtin_amdgcn_mfma_f32_16x16x32_bf16(af[mi], bf0, acc[mi][0], 0, 0, 0);
            acc[mi][1] = __builtin_amdgcn_mfma_f32_16x16x32_bf16(af[mi], bf1, acc[mi][1], 0, 0, 0);
        }
        if (kt + 1 < nkt) { bf0 = bf0n; bf1 = bf1n; }
        __syncthreads();
    }
    #undef LOADA

    // issue S tile-0 frag loads early (hide under Yt writes + barrier)
    short8 bs0 = *(const short8*)Sw0;
    short8 bs1 = *(const short8*)Sw1;

    // Phase 2a: acc -> Yt transposed (col = y-col, 4 consecutive batch rows per 8B write)
    #pragma unroll
    for (int mi = 0; mi < 4; ++mi)
        #pragma unroll
        for (int ni = 0; ni < 2; ++ni) {
            f32x4 v = acc[mi][ni];
            ushort4 st; st.x = f2b(v[0]); st.y = f2b(v[1]); st.z = f2b(v[2]); st.w = f2b(v[3]);
            int col = wc * 32 + ni * 16 + lr;
            int row0 = wr * 64 + mi * 16 + lc * 4;
            *(ushort4*)(Yt + (size_t)col * YTP + row0) = st;
        }
    __syncthreads();                                    // Yt visible; last barrier

    // Phase 2b: Zt = Yt x S, 8 K-tiles, S direct from global (prefetched), NO barriers
    f32x4 acc2[4][2] = {};
    #pragma unroll
    for (int kt = 0; kt < 8; ++kt) {
        short8 ay[4];
        #pragma unroll
        for (int mi = 0; mi < 4; ++mi)                  // a = Y^T rows (y-cols), k-contig
            ay[mi] = *(const short8*)(Yt + (size_t)(mi * 16 + lr) * YTP + kt * 32 + lc * 8);
        short8 bs0n, bs1n;
        if (kt + 1 < 8) {
            bs0n = *(const short8*)(Sw0 + (kt + 1) * 32);
            bs1n = *(const short8*)(Sw1 + (kt + 1) * 32);
        }
        #pragma unroll
        for (int mi = 0; mi < 4; ++mi) {
            acc2[mi][0] = __builtin_amdgcn_mfma_f32_16x16x32_bf16(ay[mi], bs0, acc2[mi][0], 0, 0, 0);
            acc2[mi][1] = __builtin_amdgcn_mfma_f32_16x16x32_bf16(ay[mi], bs1, acc2[mi][1], 0, 0, 0);
        }
        if (kt + 1 < 8) { bs0 = bs0n; bs1 = bs1n; }
    }

    // Epilogue: lane holds outrow lr (fixed) x 4 consecutive y-cols per frag
    #pragma unroll
    for (int ni = 0; ni < 2; ++ni) {
        int g = batch * NL + wid * 32 + ni * 16 + lr;   // global output row
        float di = dinv[g];
        #pragma unroll
        for (int mi = 0; mi < 4; ++mi) {
            int col0 = sl * 64 + mi * 16 + lc * 4;      // global col (multiple of 4)
            float4 bv;
            if (col0 < MEM) bv = *(const float4*)(bias + col0);
            else { bv.x = 0.f; bv.y = 0.f; bv.z = 0.f; bv.w = 0.f; }
            f32x4 z = acc2[mi][ni];
            float h0 = fmaxf((z[0] + 2.f * bv.x) * di, 0.f);
            float h1 = fmaxf((z[1] + 2.f * bv.y) * di, 0.f);
            float h2 = fmaxf((z[2] + 2.f * bv.z) * di, 0.f);
            float h3 = fmaxf((z[3] + 2.f * bv.w) * di, 0.f);
            if (FINAL == 0) {
                ushort4 st; st.x = f2b(h0); st.y = f2b(h1); st.z = f2b(h2); st.w = f2b(h3);
                *(ushort4*)((unsigned short*)x1b + (size_t)g * NP + col0) = st;
            } else if (col0 < MEM) {
                float4 o; o.x = h0; o.y = h1; o.z = h2; o.w = h3;
                *(float4*)(outx + (size_t)g * MEM + col0) = o;
            }
        }
    }
}

extern "C" void kernel_launch(void* const* d_in, const int* in_sizes, int n_in,
                              void* d_out, int out_size, void* d_ws, size_t ws_size,
                              hipStream_t stream) {
    const int*   words = (const int*)d_in[0];
    const int*   pos   = (const int*)d_in[1];
    const int*   ner   = (const int*)d_in[2];
    const float* adj   = (const float*)d_in[3];
    const float* embW  = (const float*)d_in[4];
    const float* posW  = (const float*)d_in[5];
    const float* nerW  = (const float*)d_in[6];
    const float* W0    = (const float*)d_in[7];
    const float* b0    = (const float*)d_in[8];
    const float* W1    = (const float*)d_in[9];
    const float* b1    = (const float*)d_in[10];
    float* out = (float*)d_out;

    char* ws = (char*)d_ws;
    size_t off = 0;
    short* W0p = (short*)(ws + off);        off += (size_t)NP * KP1 * 2;
    short* W1p = (short*)(ws + off);        off += (size_t)NP * NP * 2;
    short* X1b = (short*)(ws + off);        off += (size_t)NROWS * NP * 2;        // 16.8 MB
    float* dinv = (float*)(ws + off);       off += (size_t)NROWS * 4;
    float* rsum = (float*)(ws + off);       off += (size_t)NROWS * 4;
    unsigned* colnz = (unsigned*)(ws + off); off += (size_t)NROWS * 4;
    unsigned short* Sbf = (unsigned short*)(ws + off); off += (size_t)NROWS * NL * 2; // 16.8 MB

    prep_weights<<<(NP * KP1 + NP * NP + 255) / 256, 256, 0, stream>>>(W0, W1, W0p, W1p, colnz);
    adjrow_kernel<<<NROWS / 4, 256, 0, stream>>>(adj, dinv, rsum, Sbf, colnz);

    const int ldsB = YTOFF + 64 * YTP * 2;   // 66,560 B
    fused_kernel<0><<<NB * 4, 512, ldsB, stream>>>(nullptr, KP1, KP1 / 32, W0p, KP1,
                                                   Sbf, dinv, b0,
                                                   words, pos, ner, embW, posW, nerW,
                                                   rsum, colnz, out + OUT_X,
                                                   X1b, nullptr);
    fused_kernel<1><<<NB * 4, 512, ldsB, stream>>>(X1b, NP, NP / 32, W1p, NP,
                                                   Sbf, dinv, b1,
                                                   nullptr, nullptr, nullptr, nullptr, nullptr, nullptr,
                                                   nullptr, nullptr, nullptr,
                                                   nullptr, out);
}